// Round 2
// baseline (70.040 us; speedup 1.0000x reference)
//
#include <hip/hip_runtime.h>

// SU2 attention, MI355X — round 6: kill staging redundancy.
// Math: logits.real = dot4(q_hat, k_hat); |x*SCALE| <= 0.7071 so softmax
// needs NO max-subtraction -> partials combine by plain sum.
//
// Key observation: the WHOLE input is 256 KB (2048 j x 64 B lines).  Any
// per-head strided stage touches every line anyway, so per-block L2 fetch
// is ~256 KB regardless of heads kept.  Round-6 therefore makes each block
// stage TWO heads (adjacent 16 B in every line, one float4 load) and halves
// the block count: 512 -> 256 blocks, L2->L1 staging traffic 128 -> 64 MB.
//  * block = 1024 threads (16 waves, 4 waves/SIMD — same occupancy),
//    waves 0-7 -> head 2y, waves 8-15 -> head 2y+1.  QR = 4.
//  * LDS 80 KB: vt[2][2048] float4 + nt[2][2048] float.  1 block/CU.
//  * inner loop unchanged from round 5 (packed fp32 via ext_vector float2).
// Output PLANAR: d_out = [32768 reals (i,h,d)], then [32768 imags].

#define S 2048
#define H 8
#define QR 4            // queries per wave (register-tiled)
#define NW 16           // waves per block
#define TPB (NW * 64)   // 1024 threads
#define WPH 8           // waves per head within a block

typedef float vf2 __attribute__((ext_vector_type(2)));

__device__ inline float fast_exp2(float x) {
#if __has_builtin(__builtin_amdgcn_exp2f)
    return __builtin_amdgcn_exp2f(x);
#else
    return exp2f(x);
#endif
}

// grid = (64, 4): x = query group (8 waves x 4 q = 32 q per head), y = head-pair.
__global__ __launch_bounds__(TPB, 4) void su2_attn_fused(
        const float* __restrict__ re, const float* __restrict__ im,
        float2* __restrict__ outr, float2* __restrict__ outi) {
    __shared__ float4 vt[2][S];   // raw spinor (re0, im0, re1, im1), 64 KB
    __shared__ float  nt[2][S];   // 1/||spinor||, 16 KB

    const int y    = blockIdx.y;          // head pair: heads 2y, 2y+1
    const int lane = threadIdx.x & 63;
    const int wave = threadIdx.x >> 6;
    const int hh   = wave >> 3;           // 0 or 1: which head this wave works
    const int i_base = (blockIdx.x * WPH + (wave & 7)) * QR;

    // ---- stage BOTH heads' tables into LDS.  Input layout (j, h, d):
    // float4 at index j*4 + y covers (re[j,2y,0], re[j,2y,1], re[j,2y+1,0], re[j,2y+1,1]).
    const float4* __restrict__ re4 = (const float4*)re;
    const float4* __restrict__ im4 = (const float4*)im;
#pragma unroll
    for (int k = 0; k < S / TPB; ++k) {
        int j = k * TPB + threadIdx.x;
        float4 r = re4[j * 4 + y];
        float4 m = im4[j * 4 + y];
        // head 2y
        float ss0 = r.x * r.x + m.x * m.x + r.y * r.y + m.y * m.y;
        vt[0][j] = make_float4(r.x, m.x, r.y, m.y);
        nt[0][j] = rsqrtf(ss0);
        // head 2y+1
        float ss1 = r.z * r.z + m.z * m.z + r.w * r.w + m.w * m.w;
        vt[1][j] = make_float4(r.z, m.z, r.w, m.w);
        nt[1][j] = rsqrtf(ss1);
    }
    __syncthreads();

    // ---- query fragments with SCALE*log2(e)*inv_norm folded in
    const float c = 0.70710678118654752440f * 1.44269504088896340736f;
    vf2 qc0[QR], qc1[QR];
#pragma unroll
    for (int r = 0; r < QR; ++r) {
        float4 v = vt[hh][i_base + r];        // LDS broadcast
        float  s = nt[hh][i_base + r] * c;
        vf2 q0 = {v.x * s, v.y * s};
        vf2 q1 = {v.z * s, v.w * s};
        qc0[r] = q0;
        qc1[r] = q1;
    }

    float l[QR];
    vf2 a0[QR], a1[QR];
#pragma unroll
    for (int r = 0; r < QR; ++r) {
        l[r]  = 0.f;
        a0[r] = (vf2){0.f, 0.f};
        a1[r] = (vf2){0.f, 0.f};
    }

    // ---- main loop: j split over 64 lanes, 32 iters
#pragma unroll 4
    for (int jj = 0; jj < S / 64; ++jj) {
        int j = jj * 64 + lane;
        float4 v   = vt[hh][j];               // ds_read_b128, conflict-free
        float  inv = nt[hh][j];
        vf2 v0 = {v.x, v.y};
        vf2 v1 = {v.z, v.w};
#pragma unroll
        for (int r = 0; r < QR; ++r) {
            vf2 d2 = __builtin_elementwise_fma(qc1[r], v1, qc0[r] * v0);
            float p = fast_exp2((d2.x + d2.y) * inv);
            l[r] += p;
            vf2 pp = {p, p};
            a0[r] = __builtin_elementwise_fma(pp, v0, a0[r]);
            a1[r] = __builtin_elementwise_fma(pp, v1, a1[r]);
        }
    }

    // ---- butterfly sum all-reduce across 64 lanes (plain sums)
#pragma unroll
    for (int r = 0; r < QR; ++r) {
#pragma unroll
        for (int m = 32; m >= 1; m >>= 1) {
            l[r]    += __shfl_xor(l[r], m, 64);
            a0[r].x += __shfl_xor(a0[r].x, m, 64);
            a0[r].y += __shfl_xor(a0[r].y, m, 64);
            a1[r].x += __shfl_xor(a1[r].x, m, 64);
            a1[r].y += __shfl_xor(a1[r].y, m, 64);
        }
    }

    if (lane == 0) {
        const int h = 2 * y + hh;
#pragma unroll
        for (int r = 0; r < QR; ++r) {
            float invl = 1.0f / l[r];
            int i = i_base + r;
            // planar: real plane then imag plane, each (i, h, d) as float2
            outr[i * H + h] = make_float2(a0[r].x * invl, a1[r].x * invl);
            outi[i * H + h] = make_float2(a0[r].y * invl, a1[r].y * invl);
        }
    }
}

extern "C" void kernel_launch(void* const* d_in, const int* in_sizes, int n_in,
                              void* d_out, int out_size, void* d_ws, size_t ws_size,
                              hipStream_t stream) {
    const float* re = (const float*)d_in[0];
    const float* im = (const float*)d_in[1];
    float2* outr = (float2*)d_out;    // reals: 16384 float2
    float2* outi = outr + S * H;      // imags
    (void)d_ws; (void)ws_size;

    su2_attn_fused<<<dim3(S / (WPH * QR), H / 2), dim3(TPB), 0, stream>>>(re, im, outr, outi);
}